// Round 1
// baseline (633.450 us; speedup 1.0000x reference)
//
#include <hip/hip_runtime.h>

#define ROWS_PER_BLOCK 8
#define TPB 256

// Triple index tables for N=5, K=3, i<=j<=k (35 entries)
__constant__ unsigned char c_I3[35] = {
    0,0,0,0,0,0,0,0,0,0,0,0,0,0,0,
    1,1,1,1,1,1,1,1,1,1,
    2,2,2,2,2,2,
    3,3,3,
    4};
__constant__ unsigned char c_J3[35] = {
    0,0,0,0,0,1,1,1,1,2,2,2,3,3,4,
    1,1,1,1,2,2,2,3,3,4,
    2,2,2,3,3,4,
    3,3,4,
    4};
__constant__ unsigned char c_K3[35] = {
    0,1,2,3,4,1,2,3,4,2,3,4,3,4,4,
    1,2,3,4,2,3,4,3,4,4,
    2,3,4,3,4,4,
    3,4,4,
    4};

__global__ __launch_bounds__(TPB) void bihom_k3_kernel(
    const float* __restrict__ z_re,
    const float* __restrict__ z_im,
    float* __restrict__ out,
    int B)
{
    __shared__ float  s_zre[ROWS_PER_BLOCK * 5];
    __shared__ float  s_zim[ROWS_PER_BLOCK * 5];
    __shared__ float2 s_zz[ROWS_PER_BLOCK * 35];
    __shared__ unsigned int s_tab[1225];   // p | q<<8 | flag<<16

    const int tid = threadIdx.x;
    const int row_base = blockIdx.x * ROWS_PER_BLOCK;
    const int rows = min(ROWS_PER_BLOCK, B - row_base);

    // --- stage z for this block's rows ---
    for (int idx = tid; idx < rows * 5; idx += TPB) {
        s_zre[idx] = z_re[row_base * 5 + idx];
        s_zim[idx] = z_im[row_base * 5 + idx];
    }

    // --- build packed output-index table (same for every block, cheap) ---
    for (int t = tid; t < 1225; t += TPB) {
        int p, q;
        unsigned flag;
        if (t < 630) {
            // pairs p<=q of 35: offset(p) = p*(71-p)/2
            flag = 0u;
            int u = t;
            float s = sqrtf((float)(5041 - 8 * u));   // (71-2p)^2 at boundaries (exact)
            p = (int)((71.0f - s) * 0.5f);
            q = p + (u - p * (71 - p) / 2);
        } else {
            // strict pairs p<q: offset(p) = p*(69-p)/2
            flag = 1u;
            int u = t - 630;
            float s = sqrtf((float)(4761 - 8 * u));   // (69-2p)^2 at boundaries (exact)
            p = (int)((69.0f - s) * 0.5f);
            q = p + 1 + (u - p * (69 - p) / 2);
        }
        s_tab[t] = (unsigned)p | ((unsigned)q << 8) | (flag << 16);
    }
    __syncthreads();

    // --- compute the 35 complex triple products per row ---
    for (int idx = tid; idx < rows * 35; idx += TPB) {
        int r = idx / 35;
        int m = idx - r * 35;
        int i = c_I3[m], j = c_J3[m], k = c_K3[m];
        float ar = s_zre[r * 5 + i], ai = s_zim[r * 5 + i];
        float br = s_zre[r * 5 + j], bi = s_zim[r * 5 + j];
        float cr = s_zre[r * 5 + k], ci = s_zim[r * 5 + k];
        // (a*b) left-assoc, then *c  (matches jnp elementwise complex mul order)
        float tr = ar * br - ai * bi;
        float ti = ar * bi + ai * br;
        float zr = tr * cr - ti * ci;
        float zi = tr * ci + ti * cr;
        s_zz[idx] = make_float2(zr, zi);
    }
    __syncthreads();

    // --- main output loop: fully coalesced dword stores ---
    const long long gbase = (long long)row_base * 1225;
    const int total = rows * 1225;
    for (int idx = tid; idx < total; idx += TPB) {
        int r = idx / 1225;           // magic-mul, r in [0,8)
        int t = idx - r * 1225;
        unsigned pk = s_tab[t];
        int p = (int)(pk & 255u);
        int q = (int)((pk >> 8) & 255u);
        float2 a = s_zz[r * 35 + p];
        float2 b = s_zz[r * 35 + q];
        // zz_p * conj(zz_q): re = ar*br + ai*bi ; im = ai*br - ar*bi
        float re = a.x * b.x + a.y * b.y;
        float im = a.y * b.x - a.x * b.y;
        out[gbase + idx] = (pk & 0x10000u) ? im : re;
    }
}

extern "C" void kernel_launch(void* const* d_in, const int* in_sizes, int n_in,
                              void* d_out, int out_size, void* d_ws, size_t ws_size,
                              hipStream_t stream)
{
    const float* z_re = (const float*)d_in[0];
    const float* z_im = (const float*)d_in[1];
    float* out = (float*)d_out;
    const int B = in_sizes[0] / 5;
    const int blocks = (B + ROWS_PER_BLOCK - 1) / ROWS_PER_BLOCK;
    bihom_k3_kernel<<<blocks, TPB, 0, stream>>>(z_re, z_im, out, B);
}